// Round 1
// baseline (157.729 us; speedup 1.0000x reference)
//
#include <hip/hip_runtime.h>
#include <stdint.h>

// Problem constants (fixed shapes from setup_inputs)
#define NROW 8192   // B*S = 4*2048
#define DDIM 512
#define WPR  64     // u64 words per row (512 dims * 8 bits / 64)
#define NPAT 1024
#define NEDGE 7

// ---------------------------------------------------------------------------
// Quantize: each thread handles 8 consecutive dims -> one u64 one-hot word.
// transposed=1: output layout [w][NROW] (for x, so match-kernel row loads are
//               lane-contiguous). mapping t = w*NROW + r -> coalesced writes.
// transposed=0: output layout [p][WPR] row-major (patterns). t = p*WPR + w ->
//               coalesced reads AND writes.
// ---------------------------------------------------------------------------
__global__ __launch_bounds__(256) void quant_kernel(
    const float* __restrict__ src, const float* __restrict__ edges,
    unsigned long long* __restrict__ dst, int total, int transposed) {
  int t = blockIdx.x * 256 + threadIdx.x;
  if (t >= total) return;

  size_t src_off;
  if (transposed) {
    int w = t >> 13;           // t / NROW
    int r = t & (NROW - 1);    // t % NROW
    src_off = ((size_t)r * WPR + w) * 8;   // = r*DDIM + w*8
  } else {
    src_off = (size_t)t * 8;
  }

  const float e0 = edges[0], e1 = edges[1], e2 = edges[2], e3 = edges[3],
              e4 = edges[4], e5 = edges[5], e6 = edges[6];

  const float4* s4 = reinterpret_cast<const float4*>(src + src_off);
  float4 a = s4[0];
  float4 b = s4[1];

  auto bin = [&](float v) -> unsigned int {
    return (unsigned int)((v > e0) + (v > e1) + (v > e2) + (v > e3) +
                          (v > e4) + (v > e5) + (v > e6));
  };

  unsigned int lo = (1u << bin(a.x)) | ((1u << bin(a.y)) << 8) |
                    ((1u << bin(a.z)) << 16) | ((1u << bin(a.w)) << 24);
  unsigned int hi = (1u << bin(b.x)) | ((1u << bin(b.y)) << 8) |
                    ((1u << bin(b.z)) << 16) | ((1u << bin(b.w)) << 24);

  dst[t] = (unsigned long long)lo | ((unsigned long long)hi << 32);
}

// ---------------------------------------------------------------------------
// Match: block = 256 thr (4 waves). Block tile: 128 rows x 64 patterns.
//   wave w -> 16 patterns; lane -> 2 rows (rbase+lane, rbase+64+lane).
// Patterns staged in LDS (32KB), pattern reads are wave-uniform (broadcast).
// Row chunks loaded from transposed global layout -> coalesced.
// Counts for the 2 rows packed u16 lo/hi in one u32 (count <= 512).
// argmax with first-index tie-break via packed key (count<<10)|(1023-p),
// merged globally with atomicMax.
// ---------------------------------------------------------------------------
__global__ __launch_bounds__(256) void match_kernel(
    const unsigned long long* __restrict__ qxt,   // [WPR][NROW]
    const unsigned long long* __restrict__ qpat,  // [NPAT][WPR]
    unsigned int* __restrict__ best_packed) {     // [NROW]
  __shared__ unsigned long long lds_pat[64 * WPR];   // 32 KB

  const int tid  = threadIdx.x;
  const int lane = tid & 63;
  const int wid  = tid >> 6;
  const int rbase = blockIdx.x * 128;
  const int pbase = blockIdx.y * 64;

  // Stage 64 patterns: thread t copies 16 contiguous u64 (128B) -> coalesced.
  {
    const int p  = tid >> 2;
    const int wb = (tid & 3) * 16;
    const unsigned long long* src = qpat + (size_t)(pbase + p) * WPR + wb;
    unsigned long long* dstl = &lds_pat[p * WPR + wb];
#pragma unroll
    for (int j = 0; j < 16; ++j) dstl[j] = src[j];
  }
  __syncthreads();

  const int r0 = rbase + lane;
  const int r1 = rbase + 64 + lane;

  unsigned int counts[16];
#pragma unroll
  for (int p = 0; p < 16; ++p) counts[p] = 0;

  for (int kc = 0; kc < 8; ++kc) {
    unsigned long long rc0[8], rc1[8];
#pragma unroll
    for (int j = 0; j < 8; ++j) {
      rc0[j] = qxt[(size_t)(kc * 8 + j) * NROW + r0];
      rc1[j] = qxt[(size_t)(kc * 8 + j) * NROW + r1];
    }
    const unsigned long long* pp = &lds_pat[(wid * 16) * WPR + kc * 8];
#pragma unroll
    for (int p = 0; p < 16; ++p) {
      const unsigned long long* pw = pp + p * WPR;
      unsigned int t0 = 0, t1 = 0;
#pragma unroll
      for (int j = 0; j < 8; ++j) {
        t0 += (unsigned int)__popcll(rc0[j] & pw[j]);
        t1 += (unsigned int)__popcll(rc1[j] & pw[j]);
      }
      counts[p] += t0 + (t1 << 16);
    }
  }

  unsigned int best0 = 0, best1 = 0;
#pragma unroll
  for (int p = 0; p < 16; ++p) {
    const unsigned int pg  = (unsigned int)(pbase + wid * 16 + p);
    const unsigned int key = 1023u - pg;
    const unsigned int k0  = ((counts[p] & 0xFFFFu) << 10) | key;
    const unsigned int k1  = ((counts[p] >> 16) << 10) | key;
    best0 = k0 > best0 ? k0 : best0;
    best1 = k1 > best1 ? k1 : best1;
  }
  atomicMax(&best_packed[r0], best0);
  atomicMax(&best_packed[r1], best1);
}

// ---------------------------------------------------------------------------
// Finalize: decode packed -> (index as float, score = count/512).
// Output layout: [best_patterns (8192)] ++ [match_scores (8192)], float32.
// ---------------------------------------------------------------------------
__global__ __launch_bounds__(256) void finalize_kernel(
    const unsigned int* __restrict__ best_packed, float* __restrict__ out) {
  int i = blockIdx.x * 256 + threadIdx.x;
  if (i >= NROW) return;
  unsigned int v = best_packed[i];
  unsigned int cnt = v >> 10;
  unsigned int p = 1023u - (v & 1023u);
  out[i] = (float)p;
  out[NROW + i] = (float)cnt * (1.0f / 512.0f);
}

extern "C" void kernel_launch(void* const* d_in, const int* in_sizes, int n_in,
                              void* d_out, int out_size, void* d_ws, size_t ws_size,
                              hipStream_t stream) {
  const float* x        = (const float*)d_in[0];   // [8192, 512]
  const float* patterns = (const float*)d_in[1];   // [1024, 512]
  const float* edges    = (const float*)d_in[2];   // [7]
  float* out = (float*)d_out;                      // 16384 floats

  // Workspace layout (needs ~4.75 MB):
  unsigned long long* qxt  = (unsigned long long*)d_ws;            // 64*8192 u64 = 4 MB
  unsigned long long* qpat = qxt + (size_t)WPR * NROW;             // 1024*64 u64 = 512 KB
  unsigned int* best_packed = (unsigned int*)(qpat + (size_t)NPAT * WPR); // 32 KB

  hipMemsetAsync(best_packed, 0, NROW * sizeof(unsigned int), stream);

  {
    int total = NROW * WPR;  // 524288
    quant_kernel<<<total / 256, 256, 0, stream>>>(x, edges, qxt, total, 1);
  }
  {
    int total = NPAT * WPR;  // 65536
    quant_kernel<<<total / 256, 256, 0, stream>>>(patterns, edges, qpat, total, 0);
  }

  match_kernel<<<dim3(NROW / 128, NPAT / 64), 256, 0, stream>>>(qxt, qpat, best_packed);

  finalize_kernel<<<NROW / 256, 256, 0, stream>>>(best_packed, out);
}

// Round 2
// 155.232 us; speedup vs baseline: 1.0161x; 1.0161x over previous
//
#include <hip/hip_runtime.h>
#include <stdint.h>

// Shapes fixed by setup_inputs(): x [8192,512] f32, patterns [1024,512] f32,
// edges [7] f32. Outputs: [8192] argmax idx (as f32) ++ [8192] score (cnt/512).
#define NROW 8192
#define NPAT 1024

typedef unsigned long long u64;
typedef unsigned int u32;

// bin(v) = sum(v > e_i) -- must use exact float compares to match reference.
__device__ __forceinline__ u32 bin7(float v, float e0, float e1, float e2,
                                    float e3, float e4, float e5, float e6) {
  return (u32)((v > e0) + (v > e1) + (v > e2) + (v > e3) + (v > e4) +
               (v > e5) + (v > e6));
}

// 8 dims (two float4) -> one u64 of 8-bit one-hots.
__device__ __forceinline__ u64 onehot8(const float4& a, const float4& b,
                                       float e0, float e1, float e2, float e3,
                                       float e4, float e5, float e6) {
  u32 lo = (1u << bin7(a.x, e0, e1, e2, e3, e4, e5, e6)) |
           ((1u << bin7(a.y, e0, e1, e2, e3, e4, e5, e6)) << 8) |
           ((1u << bin7(a.z, e0, e1, e2, e3, e4, e5, e6)) << 16) |
           ((1u << bin7(a.w, e0, e1, e2, e3, e4, e5, e6)) << 24);
  u32 hi = (1u << bin7(b.x, e0, e1, e2, e3, e4, e5, e6)) |
           ((1u << bin7(b.y, e0, e1, e2, e3, e4, e5, e6)) << 8) |
           ((1u << bin7(b.z, e0, e1, e2, e3, e4, e5, e6)) << 16) |
           ((1u << bin7(b.w, e0, e1, e2, e3, e4, e5, e6)) << 24);
  return (u64)lo | ((u64)hi << 32);
}

// ---------------------------------------------------------------------------
// Prep (single dispatch):
//  blocks [0,1024):   quantize x. Thread t -> (row r = t>>5, word-pair w2 =
//                     t&31). Reads 64B contiguous per lane (wave = 4KB
//                     contiguous, coalesced). Writes one dwordx4 into the
//                     transposed paired layout qxt2[w2][NROW][2] (scattered
//                     16B stores; write side only, ~3us).
//  blocks [1024,1152): quantize patterns row-major [p][64] (read+write
//                     coalesced) and zero best_packed.
// ---------------------------------------------------------------------------
__global__ __launch_bounds__(256) void prep_kernel(
    const float* __restrict__ x, const float* __restrict__ patterns,
    const float* __restrict__ edges, u64* __restrict__ qxt2,
    u64* __restrict__ qpat, u32* __restrict__ best_packed) {
  const float e0 = edges[0], e1 = edges[1], e2 = edges[2], e3 = edges[3],
              e4 = edges[4], e5 = edges[5], e6 = edges[6];
  const int bid = blockIdx.x, tid = threadIdx.x;

  if (bid < 1024) {
    const int t = bid * 256 + tid;      // 0..262143
    const int r = t >> 5;               // row
    const int w2 = t & 31;              // word-pair (covers dims w2*16..+15)
    const float4* s4 =
        reinterpret_cast<const float4*>(x + ((size_t)r << 9) + (w2 << 4));
    float4 a = s4[0], b = s4[1], c = s4[2], d = s4[3];
    ulonglong2 v;
    v.x = onehot8(a, b, e0, e1, e2, e3, e4, e5, e6);
    v.y = onehot8(c, d, e0, e1, e2, e3, e4, e5, e6);
    *reinterpret_cast<ulonglong2*>(qxt2 + ((size_t)w2 << 14) + (r << 1)) = v;
  } else {
    const int t = (bid - 1024) * 256 + tid;  // 0..32767
    const int p = t >> 5;
    const int w2 = t & 31;
    const float4* s4 = reinterpret_cast<const float4*>(
        patterns + ((size_t)p << 9) + (w2 << 4));
    float4 a = s4[0], b = s4[1], c = s4[2], d = s4[3];
    ulonglong2 v;
    v.x = onehot8(a, b, e0, e1, e2, e3, e4, e5, e6);
    v.y = onehot8(c, d, e0, e1, e2, e3, e4, e5, e6);
    *reinterpret_cast<ulonglong2*>(qpat + ((size_t)p << 6) + (w2 << 1)) = v;
    if (t < NROW) best_packed[t] = 0;
  }
}

// ---------------------------------------------------------------------------
// Match: block = 256 thr (4 waves). Tile: 128 rows x 64 patterns.
//   wave wid -> 16 patterns; lane -> rows rbase+lane, rbase+64+lane.
// Patterns in LDS (32KB, staged conflict-free b128, inner reads wave-uniform
// -> broadcast). Row chunks: coalesced dwordx4 from qxt2 paired layout.
// Popcount accumulates straight into persistent u32 counters:
//   c = __builtin_popcount(x) + c  ==>  v_bcnt_u32_b32 c, x, c  (folded add).
// Global argmax merge via packed key (cnt<<10)|(1023-p) + atomicMax
// (first-index tie-break preserved).
// ---------------------------------------------------------------------------
__global__ __launch_bounds__(256) void match_kernel(
    const u64* __restrict__ qxt2,   // [32][NROW][2]
    const u64* __restrict__ qpat,   // [NPAT][64]
    u32* __restrict__ best_packed) {
  __shared__ u64 lds_pat[64 * 64];  // 32 KB

  const int tid = threadIdx.x;
  const int lane = tid & 63;
  const int wid = tid >> 6;
  const int rbase = blockIdx.x * 128;
  const int pbase = blockIdx.y * 64;

  // Stage 64 patterns, flat contiguous: lane i writes 16B at byte off i*16
  // -> sequential banks, conflict-free; global reads fully coalesced.
  {
    const u64* gsrc = qpat + ((size_t)pbase << 6);
#pragma unroll
    for (int i = 0; i < 8; ++i) {
      const int idx = i * 512 + tid * 2;
      *reinterpret_cast<ulonglong2*>(&lds_pat[idx]) =
          *reinterpret_cast<const ulonglong2*>(gsrc + idx);
    }
  }
  __syncthreads();

  const int r0 = rbase + lane;
  const int r1 = r0 + 64;
  const u64* xb0 = qxt2 + ((size_t)r0 << 1);
  const u64* xb1 = qxt2 + ((size_t)r1 << 1);

  u32 c0[16], c1[16];
#pragma unroll
  for (int p = 0; p < 16; ++p) {
    c0[p] = 0;
    c1[p] = 0;
  }

  for (int kc = 0; kc < 8; ++kc) {
    u64 rc0[8], rc1[8];
#pragma unroll
    for (int j2 = 0; j2 < 4; ++j2) {
      ulonglong2 v0 = *reinterpret_cast<const ulonglong2*>(
          xb0 + ((size_t)(kc * 4 + j2) << 14));
      ulonglong2 v1 = *reinterpret_cast<const ulonglong2*>(
          xb1 + ((size_t)(kc * 4 + j2) << 14));
      rc0[2 * j2] = v0.x;
      rc0[2 * j2 + 1] = v0.y;
      rc1[2 * j2] = v1.x;
      rc1[2 * j2 + 1] = v1.y;
    }
    const u64* pp = &lds_pat[(wid << 10) + (kc << 3)];
#pragma unroll
    for (int p = 0; p < 16; ++p) {
      const u64* pw = pp + (p << 6);
#pragma unroll
      for (int j = 0; j < 8; ++j) {
        const u64 m0 = rc0[j] & pw[j];
        const u64 m1 = rc1[j] & pw[j];
        c0[p] = __builtin_popcount((u32)m0) + c0[p];
        c0[p] = __builtin_popcount((u32)(m0 >> 32)) + c0[p];
        c1[p] = __builtin_popcount((u32)m1) + c1[p];
        c1[p] = __builtin_popcount((u32)(m1 >> 32)) + c1[p];
      }
    }
  }

  u32 best0 = 0, best1 = 0;
#pragma unroll
  for (int p = 0; p < 16; ++p) {
    const u32 pg = (u32)(pbase + (wid << 4) + p);
    const u32 key = 1023u - pg;
    const u32 k0 = (c0[p] << 10) | key;
    const u32 k1 = (c1[p] << 10) | key;
    best0 = k0 > best0 ? k0 : best0;
    best1 = k1 > best1 ? k1 : best1;
  }
  atomicMax(&best_packed[r0], best0);
  atomicMax(&best_packed[r1], best1);
}

// ---------------------------------------------------------------------------
// Finalize: decode packed -> (index as float, score = cnt/512).
// ---------------------------------------------------------------------------
__global__ __launch_bounds__(256) void finalize_kernel(
    const u32* __restrict__ best_packed, float* __restrict__ out) {
  const int i = blockIdx.x * 256 + threadIdx.x;
  if (i >= NROW) return;
  const u32 v = best_packed[i];
  out[i] = (float)(1023u - (v & 1023u));
  out[NROW + i] = (float)(v >> 10) * (1.0f / 512.0f);
}

extern "C" void kernel_launch(void* const* d_in, const int* in_sizes, int n_in,
                              void* d_out, int out_size, void* d_ws,
                              size_t ws_size, hipStream_t stream) {
  const float* x = (const float*)d_in[0];         // [8192, 512]
  const float* patterns = (const float*)d_in[1];  // [1024, 512]
  const float* edges = (const float*)d_in[2];     // [7]
  float* out = (float*)d_out;                     // 16384 floats

  // Workspace: qxt2 4MB ++ qpat 512KB ++ best_packed 32KB (~4.6MB total).
  u64* qxt2 = (u64*)d_ws;                          // [32][8192][2]
  u64* qpat = qxt2 + (size_t)32 * NROW * 2;        // [1024][64]
  u32* best_packed = (u32*)(qpat + (size_t)NPAT * 64);

  prep_kernel<<<1152, 256, 0, stream>>>(x, patterns, edges, qxt2, qpat,
                                        best_packed);
  match_kernel<<<dim3(NROW / 128, NPAT / 64), 256, 0, stream>>>(qxt2, qpat,
                                                                best_packed);
  finalize_kernel<<<NROW / 256, 256, 0, stream>>>(best_packed, out);
}

// Round 3
// 149.189 us; speedup vs baseline: 1.0572x; 1.0405x over previous
//
#include <hip/hip_runtime.h>
#include <stdint.h>

// Shapes fixed by setup_inputs(): x [8192,512] f32, patterns [1024,512] f32,
// edges [7] f32. Outputs: [8192] argmax idx (as f32) ++ [8192] score (cnt/512).
#define NROW 8192
#define NPAT 1024

typedef unsigned long long u64;
typedef unsigned int u32;

// bin(v) = sum(v > e_i) -- exact float compares to match reference.
__device__ __forceinline__ u32 bin7(float v, float e0, float e1, float e2,
                                    float e3, float e4, float e5, float e6) {
  return (u32)((v > e0) + (v > e1) + (v > e2) + (v > e3) + (v > e4) +
               (v > e5) + (v > e6));
}

// 8 dims (two float4) -> one u64 of 8-bit one-hots.
__device__ __forceinline__ u64 onehot8(const float4& a, const float4& b,
                                       float e0, float e1, float e2, float e3,
                                       float e4, float e5, float e6) {
  u32 lo = (1u << bin7(a.x, e0, e1, e2, e3, e4, e5, e6)) |
           ((1u << bin7(a.y, e0, e1, e2, e3, e4, e5, e6)) << 8) |
           ((1u << bin7(a.z, e0, e1, e2, e3, e4, e5, e6)) << 16) |
           ((1u << bin7(a.w, e0, e1, e2, e3, e4, e5, e6)) << 24);
  u32 hi = (1u << bin7(b.x, e0, e1, e2, e3, e4, e5, e6)) |
           ((1u << bin7(b.y, e0, e1, e2, e3, e4, e5, e6)) << 8) |
           ((1u << bin7(b.z, e0, e1, e2, e3, e4, e5, e6)) << 16) |
           ((1u << bin7(b.w, e0, e1, e2, e3, e4, e5, e6)) << 24);
  return (u64)lo | ((u64)hi << 32);
}

// ---------------------------------------------------------------------------
// Prep (single dispatch):
//  blocks [0,1024):   quantize x into transposed paired layout
//                     qxt2[w2][8192] of ulonglong2. Thread t -> w2 = t>>13,
//                     r = t&8191: WRITES are lane-contiguous (wave = 1KB
//                     coalesced); READS are one distinct aligned 64B line per
//                     lane (2KB lane stride, no amplification, no 128KB-stride
//                     L2-channel hammering like R2 had).
//  blocks [1024,1152): quantize patterns row-major [p][64] u64 (read+write
//                     coalesced) and zero best_packed.
// ---------------------------------------------------------------------------
__global__ __launch_bounds__(256) void prep_kernel(
    const float* __restrict__ x, const float* __restrict__ patterns,
    const float* __restrict__ edges, u64* __restrict__ qxt2,
    u64* __restrict__ qpat, u32* __restrict__ best_packed) {
  const float e0 = edges[0], e1 = edges[1], e2 = edges[2], e3 = edges[3],
              e4 = edges[4], e5 = edges[5], e6 = edges[6];
  const int bid = blockIdx.x, tid = threadIdx.x;

  if (bid < 1024) {
    const int t = bid * 256 + tid;   // 0..262143
    const int w2 = t >> 13;          // word-pair (dims w2*16 .. w2*16+15)
    const int r = t & 8191;          // row
    const float4* s4 =
        reinterpret_cast<const float4*>(x + ((size_t)r << 9) + (w2 << 4));
    float4 a = s4[0], b = s4[1], c = s4[2], d = s4[3];
    ulonglong2 v;
    v.x = onehot8(a, b, e0, e1, e2, e3, e4, e5, e6);
    v.y = onehot8(c, d, e0, e1, e2, e3, e4, e5, e6);
    *reinterpret_cast<ulonglong2*>(qxt2 + ((size_t)w2 << 14) + (r << 1)) = v;
  } else {
    const int t = (bid - 1024) * 256 + tid;  // 0..32767
    const int p = t >> 5;
    const int w2 = t & 31;
    const float4* s4 = reinterpret_cast<const float4*>(
        patterns + ((size_t)p << 9) + (w2 << 4));
    float4 a = s4[0], b = s4[1], c = s4[2], d = s4[3];
    ulonglong2 v;
    v.x = onehot8(a, b, e0, e1, e2, e3, e4, e5, e6);
    v.y = onehot8(c, d, e0, e1, e2, e3, e4, e5, e6);
    *reinterpret_cast<ulonglong2*>(qpat + ((size_t)p << 6) + (w2 << 1)) = v;
    if (t < NROW) best_packed[t] = 0;
  }
}

// ---------------------------------------------------------------------------
// Match, SGPR-pattern version. Block = 256 thr (4 waves), tile 128 rows x 64
// patterns; wave -> 16 patterns (pbase uniform via readfirstlane), lane -> 2
// rows. NO LDS: pattern words are wave-uniform, so they load on the scalar
// pipe (s_load_dwordx16) and feed VALU as the SGPR operand of v_and_b32.
// Inner op pair per u32-word: v_and_b32 v,s,v + v_bcnt_u32_b32 c,v,c --
// exactly 2 VALU ops per item = the 27us VALU floor, zero LDS issue.
// Global argmax merge via packed key (cnt<<10)|(1023-p) + atomicMax
// (preserves first-index tie-break).
// ---------------------------------------------------------------------------
__global__ __launch_bounds__(256) void match_kernel(
    const u64* __restrict__ qxt2,   // [32][NROW][2] pairs
    const u64* __restrict__ qpat,   // [NPAT][64]
    u32* __restrict__ best_packed) {
  const int tid = threadIdx.x;
  const int lane = tid & 63;
  // Force wave-uniformity so pattern addresses go scalar.
  const int wid = __builtin_amdgcn_readfirstlane(tid >> 6);
  const int rbase = blockIdx.x * 128;
  const int pbase = blockIdx.y * 64 + wid * 16;  // uniform

  const int r0 = rbase + lane;
  const int r1 = r0 + 64;
  const u64* xb0 = qxt2 + ((size_t)r0 << 1);
  const u64* xb1 = qxt2 + ((size_t)r1 << 1);

  u32 c0[16], c1[16];
#pragma unroll
  for (int p = 0; p < 16; ++p) {
    c0[p] = 0;
    c1[p] = 0;
  }

  // Pattern words as u32, matching row-chunk unpack order:
  // pattern p, u32 word (kc*16 + 4*j2 + q) == u64 word kc*8+2*j2+q/2, half q&1.
  const u32* patw = reinterpret_cast<const u32*>(qpat) + (size_t)pbase * 128;

  for (int kc = 0; kc < 8; ++kc) {
    u32 a0[16], a1[16];
#pragma unroll
    for (int j2 = 0; j2 < 4; ++j2) {
      ulonglong2 v0 = *reinterpret_cast<const ulonglong2*>(
          xb0 + ((size_t)(kc * 4 + j2) << 14));
      ulonglong2 v1 = *reinterpret_cast<const ulonglong2*>(
          xb1 + ((size_t)(kc * 4 + j2) << 14));
      a0[4 * j2 + 0] = (u32)v0.x;
      a0[4 * j2 + 1] = (u32)(v0.x >> 32);
      a0[4 * j2 + 2] = (u32)v0.y;
      a0[4 * j2 + 3] = (u32)(v0.y >> 32);
      a1[4 * j2 + 0] = (u32)v1.x;
      a1[4 * j2 + 1] = (u32)(v1.x >> 32);
      a1[4 * j2 + 2] = (u32)v1.y;
      a1[4 * j2 + 3] = (u32)(v1.y >> 32);
    }
#pragma unroll
    for (int p = 0; p < 16; ++p) {
      const u32* ps = patw + p * 128 + kc * 16;  // uniform -> s_load
      u32 s[16];
#pragma unroll
      for (int j = 0; j < 16; ++j) s[j] = ps[j];
#pragma unroll
      for (int j = 0; j < 16; ++j) {
        c0[p] = __popc(s[j] & a0[j]) + c0[p];
        c1[p] = __popc(s[j] & a1[j]) + c1[p];
      }
    }
  }

  u32 best0 = 0, best1 = 0;
#pragma unroll
  for (int p = 0; p < 16; ++p) {
    const u32 pg = (u32)(pbase + p);
    const u32 key = 1023u - pg;
    const u32 k0 = (c0[p] << 10) | key;
    const u32 k1 = (c1[p] << 10) | key;
    best0 = k0 > best0 ? k0 : best0;
    best1 = k1 > best1 ? k1 : best1;
  }
  atomicMax(&best_packed[r0], best0);
  atomicMax(&best_packed[r1], best1);
}

// ---------------------------------------------------------------------------
// Finalize: decode packed -> (index as float, score = cnt/512).
// ---------------------------------------------------------------------------
__global__ __launch_bounds__(256) void finalize_kernel(
    const u32* __restrict__ best_packed, float* __restrict__ out) {
  const int i = blockIdx.x * 256 + threadIdx.x;
  if (i >= NROW) return;
  const u32 v = best_packed[i];
  out[i] = (float)(1023u - (v & 1023u));
  out[NROW + i] = (float)(v >> 10) * (1.0f / 512.0f);
}

extern "C" void kernel_launch(void* const* d_in, const int* in_sizes, int n_in,
                              void* d_out, int out_size, void* d_ws,
                              size_t ws_size, hipStream_t stream) {
  const float* x = (const float*)d_in[0];         // [8192, 512]
  const float* patterns = (const float*)d_in[1];  // [1024, 512]
  const float* edges = (const float*)d_in[2];     // [7]
  float* out = (float*)d_out;                     // 16384 floats

  // Workspace: qxt2 4MB ++ qpat 512KB ++ best_packed 32KB (~4.6MB total).
  u64* qxt2 = (u64*)d_ws;                          // [32][8192][2]
  u64* qpat = qxt2 + (size_t)32 * NROW * 2;        // [1024][64]
  u32* best_packed = (u32*)(qpat + (size_t)NPAT * 64);

  prep_kernel<<<1152, 256, 0, stream>>>(x, patterns, edges, qxt2, qpat,
                                        best_packed);
  match_kernel<<<dim3(NROW / 128, NPAT / 64), 256, 0, stream>>>(qxt2, qpat,
                                                                best_packed);
  finalize_kernel<<<NROW / 256, 256, 0, stream>>>(best_packed, out);
}

// Round 5
// 94.630 us; speedup vs baseline: 1.6668x; 1.5765x over previous
//
#include <hip/hip_runtime.h>
#include <stdint.h>

// Shapes fixed by setup_inputs(): x [8192,512] f32, patterns [1024,512] f32,
// edges [7] f32. Outputs: [8192] argmax idx (as f32) ++ [8192] score (cnt/512).
//
// R5: i8 MFMA GEMM over one-hot codes, with BOTH operands expanded in
// registers from byte-codes by the identical function (operand-map symmetry
// => k-permutation invariance). No LDS, no barriers. ws kept under the
// 4.63MB proven-safe watermark from R1-R3.
#define NROW 8192
#define NPAT 1024

typedef unsigned long long u64;
typedef unsigned int u32;
typedef unsigned char u8;
typedef __attribute__((ext_vector_type(4))) int i32x4;
typedef __attribute__((ext_vector_type(16))) int i32x16;

__device__ __forceinline__ u32 bin7(float v, float e0, float e1, float e2,
                                    float e3, float e4, float e5, float e6) {
  return (u32)((v > e0) + (v > e1) + (v > e2) + (v > e3) + (v > e4) +
               (v > e5) + (v > e6));
}

// Quantize 16 consecutive dims (4 float4) -> 16 code bytes in an int4.
__device__ __forceinline__ int4 quant16(const float4* s4, float e0, float e1,
                                        float e2, float e3, float e4, float e5,
                                        float e6) {
  int4 out;
  int* od = &out.x;
#pragma unroll
  for (int q = 0; q < 4; ++q) {
    float4 a = s4[q];
    od[q] = (int)(bin7(a.x, e0, e1, e2, e3, e4, e5, e6) |
                  (bin7(a.y, e0, e1, e2, e3, e4, e5, e6) << 8) |
                  (bin7(a.z, e0, e1, e2, e3, e4, e5, e6) << 16) |
                  (bin7(a.w, e0, e1, e2, e3, e4, e5, e6) << 24));
  }
  return out;
}

// ---------------------------------------------------------------------------
// Prep (one dispatch, 1152 blocks):
//  blocks [0,1024):   x -> byte-code cells xcodeT[c][row][16], c = 16-dim
//                     chunk. i = bid*256+tid: row = i&8191, c = i>>13.
//                     Reads: each lane one distinct 64B line; writes coalesced.
//  blocks [1024,1152): patterns -> qpcT[c][pat][16]. j: pat = j>>5, c = j&31
//                     -> reads fully coalesced (consecutive lanes read
//                     consecutive 16B); writes scattered 16B (fire-and-forget).
//                     Also zeroes best_packed.
// ---------------------------------------------------------------------------
__global__ __launch_bounds__(256) void prep_kernel(
    const float* __restrict__ x, const float* __restrict__ patterns,
    const float* __restrict__ edges, u8* __restrict__ xcodeT,
    u8* __restrict__ qpcT, u32* __restrict__ best_packed) {
  const float e0 = edges[0], e1 = edges[1], e2 = edges[2], e3 = edges[3],
              e4 = edges[4], e5 = edges[5], e6 = edges[6];
  const int bid = blockIdx.x, tid = threadIdx.x;

  if (bid < 1024) {
    const int i = bid * 256 + tid;  // 0..262143
    const int row = i & 8191;
    const int c = i >> 13;
    const float4* s4 =
        reinterpret_cast<const float4*>(x + ((size_t)row << 9) + (c << 4));
    int4 out = quant16(s4, e0, e1, e2, e3, e4, e5, e6);
    *reinterpret_cast<int4*>(xcodeT + ((size_t)i << 4)) = out;
  } else {
    const int j = (bid - 1024) * 256 + tid;  // 0..32767
    const int pat = j >> 5;
    const int c = j & 31;
    const float4* s4 = reinterpret_cast<const float4*>(
        patterns + ((size_t)pat << 9) + (c << 4));
    int4 out = quant16(s4, e0, e1, e2, e3, e4, e5, e6);
    *reinterpret_cast<int4*>(qpcT + ((((size_t)c << 10) + pat) << 4)) = out;
    if (j < NROW) best_packed[j] = 0;
  }
}

// Expand 2 dims (code bytes h*2, h*2+1 of dword w) into a 16-byte one-hot
// i8 fragment: bytes 0-7 = one-hot of first dim, 8-15 = second dim.
// Used IDENTICALLY for A (patterns) and B (x rows).
__device__ __forceinline__ i32x4 expand2(u32 w, int h) {
  const u32 q0 = (w >> (h << 4)) & 0xFFu;
  const u32 q1 = (w >> ((h << 4) + 8)) & 0xFFu;
  const u64 v0 = 1ull << (q0 << 3);
  const u64 v1 = 1ull << (q1 << 3);
  i32x4 f;
  f[0] = (int)(u32)v0;
  f[1] = (int)(v0 >> 32);
  f[2] = (int)(u32)v1;
  f[3] = (int)(v1 >> 32);
  return f;
}

// ---------------------------------------------------------------------------
// Match: i8 MFMA GEMM, D[pattern][row]. Block = 256 thr (4 waves), C-tile
// 128 patterns x 128 rows; wave -> 2 pattern-groups x 2 row-groups (4 accs).
// Per 16-dim chunk: 4 coalesced dwordx4 code loads (L2-resident), in-register
// one-hot expansion (expand2 for all four operand cells), 16 MFMAs.
// No LDS, no barriers. Epilogue: verified C/D map col=lane&31,
// row=(reg&3)+8*(reg>>2)+4*(lane>>5); packed-key atomicMax preserves
// first-index argmax.
// ---------------------------------------------------------------------------
__global__ __launch_bounds__(256, 2) void match_kernel(
    const u8* __restrict__ xcodeT,  // [32][8192][16]
    const u8* __restrict__ qpcT,    // [32][1024][16]
    u32* __restrict__ best_packed) {
  const int tid = threadIdx.x;
  const int lane = tid & 63;
  const int h = lane >> 5;
  const int wid = tid >> 6;
  const int rgb = blockIdx.x;  // 0..63 -> 128 rows
  const int pgb = blockIdx.y;  // 0..7  -> 128 patterns

  const int pgs0 = 2 * (wid & 1);
  const int rg0 = 2 * (wid >> 1);
  const int row0 = rgb * 128 + rg0 * 32 + (lane & 31);
  const int row1 = row0 + 32;
  const int m0 = pgb * 128 + pgs0 * 32 + (lane & 31);
  const int m1 = m0 + 32;

  const u8* pR0 = xcodeT + ((size_t)row0 << 4);
  const u8* pR1 = xcodeT + ((size_t)row1 << 4);
  const u8* pP0 = qpcT + ((size_t)m0 << 4);
  const u8* pP1 = qpcT + ((size_t)m1 << 4);

  i32x16 acc00 = {0};  // (pattern-group 0, row0)
  i32x16 acc10 = {0};  // (pattern-group 1, row0)
  i32x16 acc01 = {0};  // (pattern-group 0, row1)
  i32x16 acc11 = {0};  // (pattern-group 1, row1)

  i32x4 cR0 = *reinterpret_cast<const i32x4*>(pR0);
  i32x4 cR1 = *reinterpret_cast<const i32x4*>(pR1);
  i32x4 cP0 = *reinterpret_cast<const i32x4*>(pP0);
  i32x4 cP1 = *reinterpret_cast<const i32x4*>(pP1);

  for (int c = 0; c < 32; ++c) {
    i32x4 nR0, nR1, nP0, nP1;
    if (c < 31) {
      // chunk stride: xcodeT 8192*16 = 1<<17 bytes; qpcT 1024*16 = 1<<14.
      nR0 = *reinterpret_cast<const i32x4*>(pR0 + ((size_t)(c + 1) << 17));
      nR1 = *reinterpret_cast<const i32x4*>(pR1 + ((size_t)(c + 1) << 17));
      nP0 = *reinterpret_cast<const i32x4*>(pP0 + ((size_t)(c + 1) << 14));
      nP1 = *reinterpret_cast<const i32x4*>(pP1 + ((size_t)(c + 1) << 14));
    }
#pragma unroll
    for (int ks = 0; ks < 4; ++ks) {
      const i32x4 a0 = expand2((u32)cP0[ks], h);
      const i32x4 a1 = expand2((u32)cP1[ks], h);
      const i32x4 b0 = expand2((u32)cR0[ks], h);
      const i32x4 b1 = expand2((u32)cR1[ks], h);
      acc00 = __builtin_amdgcn_mfma_i32_32x32x32_i8(a0, b0, acc00, 0, 0, 0);
      acc10 = __builtin_amdgcn_mfma_i32_32x32x32_i8(a1, b0, acc10, 0, 0, 0);
      acc01 = __builtin_amdgcn_mfma_i32_32x32x32_i8(a0, b1, acc01, 0, 0, 0);
      acc11 = __builtin_amdgcn_mfma_i32_32x32x32_i8(a1, b1, acc11, 0, 0, 0);
    }
    if (c < 31) {
      cR0 = nR0;
      cR1 = nR1;
      cP0 = nP0;
      cP1 = nP1;
    }
  }

  // Epilogue: lane owns D col = lane&31 (its row0/row1); D row = pattern
  // offset pl = (reg&3)+8*(reg>>2)+4*h within the 32-pattern group.
  const int pbase = pgb * 128 + pgs0 * 32;
  u32 best0 = 0, best1 = 0;
#pragma unroll
  for (int r = 0; r < 16; ++r) {
    const int pl = (r & 3) + 8 * (r >> 2) + 4 * h;
    const u32 key0 = 1023u - (u32)(pbase + pl);
    const u32 key1 = 1023u - (u32)(pbase + 32 + pl);
    const u32 k00 = (((u32)acc00[r]) << 10) | key0;
    const u32 k10 = (((u32)acc10[r]) << 10) | key1;
    const u32 k01 = (((u32)acc01[r]) << 10) | key0;
    const u32 k11 = (((u32)acc11[r]) << 10) | key1;
    best0 = k00 > best0 ? k00 : best0;
    best0 = k10 > best0 ? k10 : best0;
    best1 = k01 > best1 ? k01 : best1;
    best1 = k11 > best1 ? k11 : best1;
  }
  atomicMax(&best_packed[row0], best0);
  atomicMax(&best_packed[row1], best1);
}

// ---------------------------------------------------------------------------
// Finalize: decode packed -> (index as float, score = cnt/512).
// ---------------------------------------------------------------------------
__global__ __launch_bounds__(256) void finalize_kernel(
    const u32* __restrict__ best_packed, float* __restrict__ out) {
  const int i = blockIdx.x * 256 + threadIdx.x;
  if (i >= NROW) return;
  const u32 v = best_packed[i];
  out[i] = (float)(1023u - (v & 1023u));
  out[NROW + i] = (float)(v >> 10) * (1.0f / 512.0f);
}

extern "C" void kernel_launch(void* const* d_in, const int* in_sizes, int n_in,
                              void* d_out, int out_size, void* d_ws,
                              size_t ws_size, hipStream_t stream) {
  const float* x = (const float*)d_in[0];         // [8192, 512]
  const float* patterns = (const float*)d_in[1];  // [1024, 512]
  const float* edges = (const float*)d_in[2];     // [7]
  float* out = (float*)d_out;                     // 16384 floats

  // Workspace: xcodeT 4MB ++ qpcT 512KB ++ best_packed 32KB = 4.53MB
  // (below the 4.63MB proven-safe watermark from R1-R3).
  u8* xcodeT = (u8*)d_ws;                        // [32][8192][16]
  u8* qpcT = xcodeT + (size_t)32 * NROW * 16;    // [32][1024][16]
  u32* best_packed = (u32*)(qpcT + (size_t)32 * NPAT * 16);

  prep_kernel<<<1152, 256, 0, stream>>>(x, patterns, edges, xcodeT, qpcT,
                                        best_packed);
  match_kernel<<<dim3(64, 8), 256, 0, stream>>>(xcodeT, qpcT, best_packed);
  finalize_kernel<<<NROW / 256, 256, 0, stream>>>(best_packed, out);
}